// Round 6
// baseline (532.842 us; speedup 1.0000x reference)
//
#include <hip/hip_runtime.h>

// Problem constants
static constexpr int kBS    = 8;
static constexpr int kNROI  = 128;
static constexpr int kR     = kBS * kNROI;   // 1024 rows
static constexpr int kCH    = 1280;
static constexpr int kH     = 64;
static constexpr int kW     = 64;
static constexpr int kPIX   = kH * kW;       // 4096
static constexpr int kINNER = 5120;
static constexpr int kOUTC  = 1024;
static constexpr int kXE    = 2 * kOUTC;     // 2048 concat width

typedef _Float16 half8 __attribute__((ext_vector_type(8)));   // f16x8 MFMA A/B frag
typedef float floatx4 __attribute__((ext_vector_type(4)));    // MFMA C/D frag

// Async global->LDS DMA, 16B per lane. LDS dest must be wave-uniform base;
// HW writes lane i at base + i*16 (m97-verified idiom).
__device__ __forceinline__ void gl_lds16(const _Float16* g, _Float16* l) {
    __builtin_amdgcn_global_load_lds(
        (const __attribute__((address_space(1))) void*)g,
        (__attribute__((address_space(3))) void*)l, 16, 0, 0);
}

// ---------------------------------------------------------------------------
// Elementwise convert z: fp32 -> f16 (keeps native (b, c, p) layout).
// ---------------------------------------------------------------------------
__global__ __launch_bounds__(256) void convert_f16(const float* __restrict__ src,
                                                   _Float16* __restrict__ dst) {
    const size_t i = ((size_t)blockIdx.x * 256 + threadIdx.x) * 8;
    const float4 a = *(const float4*)(src + i);
    const float4 b = *(const float4*)(src + i + 4);
    half8 o;
    o[0] = (_Float16)a.x; o[1] = (_Float16)a.y; o[2] = (_Float16)a.z; o[3] = (_Float16)a.w;
    o[4] = (_Float16)b.x; o[5] = (_Float16)b.y; o[6] = (_Float16)b.z; o[7] = (_Float16)b.w;
    *(half8*)(dst + i) = o;
}

// ---------------------------------------------------------------------------
// ROI point lists (separable bilinear weights)
// ---------------------------------------------------------------------------
struct RoiLists {
    int   yidx[16], xidx[16];
    float ywt[16], xwt[16];
    int   ny, nx;
    float invCount;
};

__device__ inline void build_lists(const float* __restrict__ bboxes, int r, RoiLists* L) {
    const float x1 = bboxes[r * 4 + 0] * 0.125f - 0.5f;
    const float y1 = bboxes[r * 4 + 1] * 0.125f - 0.5f;
    const float x2 = bboxes[r * 4 + 2] * 0.125f - 0.5f;
    const float y2 = bboxes[r * 4 + 3] * 0.125f - 0.5f;
    const float rw = x2 - x1, rh = y2 - y1;
    const float gwf = fminf(fmaxf(ceilf(rw), 1.0f), 8.0f);
    const float ghf = fminf(fmaxf(ceilf(rh), 1.0f), 8.0f);
    const int gw = (int)gwf, gh = (int)ghf;
    L->invCount = 1.0f / (gwf * ghf);
    for (int g = 0; g < gh; ++g) {
        const float c   = y1 + ((float)g + 0.5f) * rh / ghf;
        const bool oob  = (c < -1.0f) || (c > 64.0f);
        const float cc  = fmaxf(c, 0.0f);
        const float lo0 = floorf(cc);
        const bool hic  = (lo0 >= 63.0f);
        const int lo    = (int)fminf(lo0, 63.0f);
        const int hi    = (int)fminf(lo0 + 1.0f, 63.0f);
        const float fr  = hic ? 0.0f : (cc - lo0);
        const float m   = oob ? 0.0f : 1.0f;
        L->yidx[2 * g]     = lo; L->ywt[2 * g]     = m * (1.0f - fr);
        L->yidx[2 * g + 1] = hi; L->ywt[2 * g + 1] = m * fr;
    }
    L->ny = 2 * gh;
    for (int g = 0; g < gw; ++g) {
        const float c   = x1 + ((float)g + 0.5f) * rw / gwf;
        const bool oob  = (c < -1.0f) || (c > 64.0f);
        const float cc  = fmaxf(c, 0.0f);
        const float lo0 = floorf(cc);
        const bool hic  = (lo0 >= 63.0f);
        const int lo    = (int)fminf(lo0, 63.0f);
        const int hi    = (int)fminf(lo0 + 1.0f, 63.0f);
        const float fr  = hic ? 0.0f : (cc - lo0);
        const float m   = oob ? 0.0f : 1.0f;
        L->xidx[2 * g]     = lo; L->xwt[2 * g]     = m * (1.0f - fr);
        L->xidx[2 * g + 1] = hi; L->xwt[2 * g + 1] = m * fr;
    }
    L->nx = 2 * gw;
}

// ---------------------------------------------------------------------------
// Build dense ROI weight image w[r][p] (f16, invCount folded in).
// fp32 accumulation in LDS: adjacent samples can land in the same cell, so
// contributions must ADD (scatter with last-write-wins would be wrong).
// ---------------------------------------------------------------------------
__global__ __launch_bounds__(256) void build_w(const float* __restrict__ bboxes,
                                               _Float16* __restrict__ wbuf) {
    __shared__ float wrow[kPIX];
    __shared__ RoiLists L;
    const int r = blockIdx.x;
    const int t = threadIdx.x;
    for (int i = t; i < kPIX; i += 256) wrow[i] = 0.f;
    if (t == 0) build_lists(bboxes, r, &L);
    __syncthreads();
    if (t == 0) {
        for (int iy = 0; iy < L.ny; ++iy) {
            const float wy = L.ywt[iy];
            const int base = L.yidx[iy] * kW;
            for (int ix = 0; ix < L.nx; ++ix)
                wrow[base + L.xidx[ix]] += wy * L.xwt[ix];
        }
    }
    __syncthreads();
    const float ic = L.invCount;
    _Float16* wr = wbuf + (size_t)r * kPIX;
    for (int i = t; i < kPIX; i += 256) wr[i] = (_Float16)(wrow[i] * ic);
}

// Fallback: gather directly from fp32 z (b,c,H,W) -> f16 x (if ws too small)
__global__ __launch_bounds__(256) void roi_gather_direct(const float* __restrict__ z,
                                                         const float* __restrict__ bboxes,
                                                         _Float16* __restrict__ x) {
    const int r = blockIdx.x;
    const int b = r >> 7;
    __shared__ RoiLists L;
    if (threadIdx.x == 0) build_lists(bboxes, r, &L);
    __syncthreads();
    const int ny = L.ny, nx = L.nx;
    const float ic = L.invCount;
    const float* zb = z + (size_t)b * kCH * kPIX;
    for (int c = threadIdx.x; c < kCH; c += 256) {
        const float* zc = zb + (size_t)c * kPIX;
        float acc = 0.f;
        for (int iy = 0; iy < ny; ++iy) {
            const float wy = L.ywt[iy];
            const int base = L.yidx[iy] * kW;
            for (int ix = 0; ix < nx; ++ix)
                acc += wy * L.xwt[ix] * zc[base + L.xidx[ix]];
        }
        x[(size_t)r * kCH + c] = (_Float16)(acc * ic);
    }
}

// ---------------------------------------------------------------------------
// Weight transpose+convert: W (K x N) fp32 -> Wt (N x K) f16
// ---------------------------------------------------------------------------
__global__ __launch_bounds__(256) void convert_transpose(const float* __restrict__ W,
                                                         _Float16* __restrict__ Wt,
                                                         int K, int N) {
    __shared__ float tile[32][33];  // [k][n]
    const int n0 = blockIdx.x * 32;
    const int k0 = blockIdx.y * 32;
    const int tx = threadIdx.x;     // 0..31
    const int ty = threadIdx.y;     // 0..7
#pragma unroll
    for (int i = 0; i < 4; ++i)
        tile[ty + i * 8][tx] = W[(size_t)(k0 + ty + i * 8) * N + n0 + tx];
    __syncthreads();
#pragma unroll
    for (int i = 0; i < 4; ++i)
        Wt[(size_t)(n0 + ty + i * 8) * K + k0 + tx] = (_Float16)tile[tx][ty + i * 8];
}

// ---------------------------------------------------------------------------
// Batched split-K f16 MFMA GEMM (NT): per (batch b, split s):
//   P[b*NSPLIT+s] = A_b[:, s*Ks:(s+1)*Ks] @ Bt_b[:, same]^T  (fp32 partials)
// 128x128 tile, BK=32, 256 threads = 4 waves, each wave 4x4 of 16x16x32.
// Staging via global_load_lds (16B/lane DMA; LDS layout = chunk order).
// gridDim.z = batches * NSPLIT. Astride/Bstride in elements (0 => unbatched).
// ---------------------------------------------------------------------------
template <int NSPLIT>
__global__ __launch_bounds__(256) void gemm_f16_skb(const _Float16* __restrict__ A,
                                                    const _Float16* __restrict__ Bt,
                                                    float* __restrict__ P,
                                                    int Kfull,
                                                    size_t Astride, size_t Bstride) {
    __shared__ _Float16 As[128 * 32];   // [m][k] row-major
    __shared__ _Float16 Bs[128 * 32];   // [n][k] row-major
    const int t    = threadIdx.x;
    const int lane = t & 63;
    const int wave = t >> 6;
    const int m0 = blockIdx.y * 128, n0 = blockIdx.x * 128;
    const int Ksplit = Kfull / NSPLIT;
    const int s  = blockIdx.z % NSPLIT;
    const int b  = blockIdx.z / NSPLIT;
    const int Nn = gridDim.x * 128;
    const int Mm = gridDim.y * 128;
    float* Pp = P + (size_t)blockIdx.z * Mm * Nn;
    const _Float16* Ab  = A + (size_t)b * Astride;
    const _Float16* Btb = Bt + (size_t)b * Bstride;

    // Staging: 512 16B chunks per tile; each thread owns chunks c0=t, c1=t+256.
    const int c0 = t, c1 = t + 256;
    const _Float16* Ag0 = Ab + (size_t)(m0 + (c0 >> 2)) * Kfull + (c0 & 3) * 8 + s * Ksplit;
    const _Float16* Ag1 = Ab + (size_t)(m0 + (c1 >> 2)) * Kfull + (c1 & 3) * 8 + s * Ksplit;
    const _Float16* Bg0 = Btb + (size_t)(n0 + (c0 >> 2)) * Kfull + (c0 & 3) * 8 + s * Ksplit;
    const _Float16* Bg1 = Btb + (size_t)(n0 + (c1 >> 2)) * Kfull + (c1 & 3) * 8 + s * Ksplit;
    const int ldsBase = (t & ~63) * 8;   // wave-uniform chunk base (elements)

    const int wm = (wave >> 1) * 64;       // wave row offset in tile
    const int wn = (wave & 1) * 64;        // wave col offset in tile
    const int fm = lane & 15;              // fragment row/col within 16
    const int kq = (lane >> 4) * 8;        // fragment k offset

    floatx4 acc[4][4];
#pragma unroll
    for (int i = 0; i < 4; ++i)
#pragma unroll
        for (int j = 0; j < 4; ++j) acc[i][j] = (floatx4){0.f, 0.f, 0.f, 0.f};

    for (int k0i = 0; k0i < Ksplit; k0i += 32) {
        __syncthreads();                     // prior compute done before overwrite
        gl_lds16(Ag0 + k0i, &As[ldsBase]);
        gl_lds16(Ag1 + k0i, &As[ldsBase + 2048]);
        gl_lds16(Bg0 + k0i, &Bs[ldsBase]);
        gl_lds16(Bg1 + k0i, &Bs[ldsBase + 2048]);
        __syncthreads();                     // barrier drains vmcnt -> LDS valid

        half8 af[4], bfv[4];
#pragma unroll
        for (int i = 0; i < 4; ++i)
            af[i] = *(const half8*)&As[(wm + i * 16 + fm) * 32 + kq];
#pragma unroll
        for (int j = 0; j < 4; ++j)
            bfv[j] = *(const half8*)&Bs[(wn + j * 16 + fm) * 32 + kq];
#pragma unroll
        for (int i = 0; i < 4; ++i)
#pragma unroll
            for (int j = 0; j < 4; ++j)
                acc[i][j] = __builtin_amdgcn_mfma_f32_16x16x32_f16(af[i], bfv[j], acc[i][j], 0, 0, 0);
    }

    // Epilogue: raw fp32 partial store. C/D layout col = lane&15, row = (lane>>4)*4 + rr
    const int qr = (lane >> 4) * 4;
#pragma unroll
    for (int j = 0; j < 4; ++j) {
        const int col = n0 + wn + j * 16 + fm;
#pragma unroll
        for (int i = 0; i < 4; ++i) {
            const int row = m0 + wm + i * 16 + qr;
#pragma unroll
            for (int rr = 0; rr < 4; ++rr)
                Pp[(size_t)(row + rr) * Nn + col] = acc[i][j][rr];
        }
    }
}

// ---------------------------------------------------------------------------
// Split-K reduce + bias + (relu) + convert (unbatched planes [s][M][N]).
// ---------------------------------------------------------------------------
template <bool RELU, bool F16OUT, int NSPLIT>
__global__ __launch_bounds__(256) void reduce_splitk(const float* __restrict__ P,
                                                     const float* __restrict__ bias,
                                                     void* __restrict__ Cout,
                                                     int Nn, int ldc) {
    const size_t idx = ((size_t)blockIdx.x * 256 + threadIdx.x) * 4;
    const size_t MN  = (size_t)gridDim.x * 1024;
    const int m = (int)(idx / (size_t)Nn);
    const int n = (int)(idx % (size_t)Nn);
    float4 acc = *(const float4*)(P + idx);
#pragma unroll
    for (int s = 1; s < NSPLIT; ++s) {
        const float4 v = *(const float4*)(P + (size_t)s * MN + idx);
        acc.x += v.x; acc.y += v.y; acc.z += v.z; acc.w += v.w;
    }
    const float4 b4 = *(const float4*)(bias + n);
    acc.x += b4.x; acc.y += b4.y; acc.z += b4.z; acc.w += b4.w;
    if (RELU) {
        acc.x = fmaxf(acc.x, 0.f); acc.y = fmaxf(acc.y, 0.f);
        acc.z = fmaxf(acc.z, 0.f); acc.w = fmaxf(acc.w, 0.f);
    }
    if (F16OUT) {
        union { _Float16 h[4]; uint2 u; } pk;
        pk.h[0] = (_Float16)acc.x; pk.h[1] = (_Float16)acc.y;
        pk.h[2] = (_Float16)acc.z; pk.h[3] = (_Float16)acc.w;
        *(uint2*)((_Float16*)Cout + (size_t)m * ldc + n) = pk.u;
    } else {
        *(float4*)((float*)Cout + (size_t)m * ldc + n) = acc;
    }
}

// Reduce for the batched ROI GEMM: P layout [b][s=4][128][1280] -> x (1024x1280 f16)
__global__ __launch_bounds__(256) void reduce_roi(const float* __restrict__ P,
                                                  _Float16* __restrict__ x) {
    const size_t idx = ((size_t)blockIdx.x * 256 + threadIdx.x) * 4;  // over 1024*1280
    const int r = (int)(idx / kCH);
    const int n = (int)(idx % kCH);
    const int b = r >> 7, m = r & 127;
    const size_t plane = (size_t)128 * kCH;
    const float* Pb = P + (size_t)b * 4 * plane + (size_t)m * kCH + n;
    float4 acc = *(const float4*)(Pb);
#pragma unroll
    for (int s = 1; s < 4; ++s) {
        const float4 v = *(const float4*)(Pb + s * plane);
        acc.x += v.x; acc.y += v.y; acc.z += v.z; acc.w += v.w;
    }
    union { _Float16 h[4]; uint2 u; } pk;
    pk.h[0] = (_Float16)acc.x; pk.h[1] = (_Float16)acc.y;
    pk.h[2] = (_Float16)acc.z; pk.h[3] = (_Float16)acc.w;
    *(uint2*)(x + (size_t)r * kCH + n) = pk.u;
}

// ---------------------------------------------------------------------------
// Size-embedding MLP: 2 -> 64 -> 256 -> 1024, one block per ROI row.
// Writes f16 into right half of xe (ld = 2048, cols 1024..2047).
// ---------------------------------------------------------------------------
__global__ __launch_bounds__(256) void size_mlp(const float* __restrict__ bboxes,
                                                const float* __restrict__ S1,
                                                const float* __restrict__ sb1,
                                                const float* __restrict__ S2,
                                                const float* __restrict__ sb2,
                                                const float* __restrict__ S3,
                                                const float* __restrict__ sb3,
                                                _Float16* __restrict__ xe) {
    const int r = blockIdx.x;
    const int t = threadIdx.x;
    __shared__ float h1[64];
    __shared__ float h2[256];
    const float szh = bboxes[r * 4 + 3] - bboxes[r * 4 + 1];
    const float szw = bboxes[r * 4 + 2] - bboxes[r * 4 + 0];
    if (t < 64) {
        const float v = szh * S1[t] + szw * S1[64 + t] + sb1[t];
        h1[t] = fmaxf(v, 0.0f);
    }
    __syncthreads();
    {
        float acc = sb2[t];
#pragma unroll 8
        for (int k = 0; k < 64; ++k) acc += h1[k] * S2[k * 256 + t];
        h2[t] = fmaxf(acc, 0.0f);
    }
    __syncthreads();
#pragma unroll
    for (int q = 0; q < 4; ++q) {
        const int j = t + q * 256;
        float acc = sb3[j];
#pragma unroll 8
        for (int k = 0; k < 256; ++k) acc += h2[k] * S3[k * 1024 + j];
        xe[(size_t)r * kXE + kOUTC + j] = (_Float16)acc;
    }
}

// ---------------------------------------------------------------------------
extern "C" void kernel_launch(void* const* d_in, const int* in_sizes, int n_in,
                              void* d_out, int out_size, void* d_ws, size_t ws_size,
                              hipStream_t stream) {
    (void)in_sizes; (void)n_in; (void)out_size;
    const float* z   = (const float*)d_in[0];
    const float* bb  = (const float*)d_in[1];
    const float* W1  = (const float*)d_in[2];
    const float* b1  = (const float*)d_in[3];
    const float* W2  = (const float*)d_in[4];
    const float* b2  = (const float*)d_in[5];
    const float* S1  = (const float*)d_in[6];
    const float* sb1 = (const float*)d_in[7];
    const float* S2  = (const float*)d_in[8];
    const float* sb2 = (const float*)d_in[9];
    const float* S3  = (const float*)d_in[10];
    const float* sb3 = (const float*)d_in[11];
    const float* O   = (const float*)d_in[12];
    const float* ob  = (const float*)d_in[13];
    float* out = (float*)d_out;

    char* ws = (char*)d_ws;
    size_t off = 0;
    auto alloc = [&](size_t bytes) {
        void* p = ws + off;
        off += (bytes + 255) & ~(size_t)255;
        return p;
    };
    _Float16* x   = (_Float16*)alloc((size_t)kR * kCH * 2);       //  2.6 MB
    _Float16* h   = (_Float16*)alloc((size_t)kR * kINNER * 2);    // 10.5 MB
    _Float16* xe  = (_Float16*)alloc((size_t)kR * kXE * 2);       //  4.2 MB
    _Float16* W1t = (_Float16*)alloc((size_t)kINNER * kCH * 2);   // 13.1 MB
    _Float16* W2t = (_Float16*)alloc((size_t)kOUTC * kINNER * 2); // 10.5 MB
    _Float16* Ot  = (_Float16*)alloc((size_t)kOUTC * kXE * 2);    //  4.2 MB
    float*    P   = (float*)alloc((size_t)2 * kR * kINNER * 4);   // 41.9 MB (max partials)
    _Float16* wbuf = (_Float16*)alloc((size_t)kR * kPIX * 2);     //  8.4 MB
    const size_t zfBytes = (size_t)kBS * kCH * kPIX * 2;          // 83.9 MB
    _Float16* zf = (_Float16*)(ws + off);
    const bool fits = (off + zfBytes) <= ws_size;

    // Weight conversions (fp32 -> f16, transposed to N x K)
    hipLaunchKernelGGL(convert_transpose, dim3(kINNER / 32, kCH / 32), dim3(32, 8), 0, stream,
                       W1, W1t, kCH, kINNER);
    hipLaunchKernelGGL(convert_transpose, dim3(kOUTC / 32, kINNER / 32), dim3(32, 8), 0, stream,
                       W2, W2t, kINNER, kOUTC);
    hipLaunchKernelGGL(convert_transpose, dim3(kOUTC / 32, kXE / 32), dim3(32, 8), 0, stream,
                       O, Ot, kXE, kOUTC);

    // 1) ROI-align features -> x (1024 x 1280 f16)
    if (fits) {
        // z fp32 -> f16 (native layout), dense ROI weights, batched GEMM over pixels
        hipLaunchKernelGGL(convert_f16, dim3((size_t)kBS * kCH * kPIX / (256 * 8)), dim3(256),
                           0, stream, z, zf);
        hipLaunchKernelGGL(build_w, dim3(kR), dim3(256), 0, stream, bb, wbuf);
        // per batch: (128 x 4096) @ (1280 x 4096)^T, split-K x4; grid z = 8*4
        hipLaunchKernelGGL((gemm_f16_skb<4>), dim3(kCH / 128, 1, kBS * 4), dim3(256), 0,
                           stream, wbuf, zf, P, kPIX,
                           (size_t)kNROI * kPIX, (size_t)kCH * kPIX);
        hipLaunchKernelGGL(reduce_roi, dim3((size_t)kR * kCH / 1024), dim3(256), 0, stream,
                           P, x);
    } else {
        hipLaunchKernelGGL(roi_gather_direct, dim3(kR), dim3(256), 0, stream, z, bb, x);
    }

    // 2) size-embedding MLP -> xe[:, 1024:2048] (f16)
    hipLaunchKernelGGL(size_mlp, dim3(kR), dim3(256), 0, stream,
                       bb, S1, sb1, S2, sb2, S3, sb3, xe);

    // 3) h = relu(x @ W1 + b1)   (1024x1280)@(1280x5120), split-K x2 -> f16
    hipLaunchKernelGGL((gemm_f16_skb<2>), dim3(kINNER / 128, kR / 128, 2), dim3(256), 0,
                       stream, x, W1t, P, kCH, (size_t)0, (size_t)0);
    hipLaunchKernelGGL((reduce_splitk<true, true, 2>),
                       dim3((size_t)kR * kINNER / 1024), dim3(256), 0, stream,
                       P, b1, h, kINNER, kINNER);

    // 4) xe[:, 0:1024] = h @ W2 + b2   (1024x5120)@(5120x1024), split-K x8 -> f16
    hipLaunchKernelGGL((gemm_f16_skb<8>), dim3(kOUTC / 128, kR / 128, 8), dim3(256), 0,
                       stream, h, W2t, P, kINNER, (size_t)0, (size_t)0);
    hipLaunchKernelGGL((reduce_splitk<false, true, 8>),
                       dim3((size_t)kR * kOUTC / 1024), dim3(256), 0, stream,
                       P, b2, xe, kOUTC, kXE);

    // 5) out = xe @ O + ob   (1024x2048)@(2048x1024), split-K x4 -> fp32
    hipLaunchKernelGGL((gemm_f16_skb<4>), dim3(kOUTC / 128, kR / 128, 4), dim3(256), 0,
                       stream, xe, Ot, P, kXE, (size_t)0, (size_t)0);
    hipLaunchKernelGGL((reduce_splitk<false, false, 4>),
                       dim3((size_t)kR * kOUTC / 1024), dim3(256), 0, stream,
                       P, ob, out, kOUTC, kOUTC);
}